// Round 5
// baseline (320.237 us; speedup 1.0000x reference)
//
#include <hip/hip_runtime.h>
#include <hip/hip_bf16.h>

#define D_BLADE 256
#define D_FFN 1024
#define N_TOK 8192
#define M_TOTAL (N_TOK * 8)

#define BM 64
#define FC 64                     // F per chunk (16 chunks)
#define SN_BYTES (BM * 512)       // 64 rows x 512B (256 bf16), swizzled
#define SH_BYTES (BM * 128)       // 64 rows x 128B (64 bf16) per buffer
#define LDS_BYTES (SN_BYTES + 2 * SH_BYTES)   // 49152 -> 3 blocks/CU

typedef __attribute__((ext_vector_type(8))) short bf16x8;
typedef __attribute__((ext_vector_type(4))) float f32x4;

__device__ __forceinline__ float sigm(float v) { return 1.0f / (1.0f + __expf(-v)); }

// ---------------- weights fp32 -> bf16 ----------------
__global__ __launch_bounds__(256) void wconv_kernel(const float* __restrict__ g,
                                                    const float* __restrict__ u,
                                                    const float* __restrict__ dn,
                                                    __hip_bfloat16* __restrict__ gb,
                                                    __hip_bfloat16* __restrict__ ub,
                                                    __hip_bfloat16* __restrict__ db) {
    int i = blockIdx.x * 256 + threadIdx.x;
    gb[i] = __float2bfloat16(g[i]);
    ub[i] = __float2bfloat16(u[i]);
    db[i] = __float2bfloat16(dn[i]);
}

// ---------------- geometric product + mix + LayerNorm -> normed (bf16) ----------------
__global__ __launch_bounds__(256) void geo_ln_kernel(
    const float* __restrict__ x, const float* __restrict__ iw,
    const float* __restrict__ sg, const float* __restrict__ gg,
    const float* __restrict__ lnw, const float* __restrict__ lnb,
    __hip_bfloat16* __restrict__ nrm)
{
    static constexpr int CK[64] = {
        0,1,2,3,4,5,6,7,
        1,0,4,5,2,3,7,6,
        2,4,0,6,1,7,3,5,
        3,5,6,0,7,1,2,4,
        4,2,1,7,0,6,5,3,
        5,3,7,1,6,0,4,2,
        6,7,3,2,5,4,0,1,
        7,6,5,4,3,2,1,0};
    __shared__ float coefs[64];
    __shared__ float redA[4][8];
    __shared__ float redB[4][8];
    const int tid = threadIdx.x;
    const int n = blockIdx.x;
    if (tid < 64) coefs[tid] = sg[tid] * sigm(iw[tid]);
    __syncthreads();

    const float* xp = x + (size_t)n * (8 * D_BLADE) + tid;
    float xa[8];
#pragma unroll
    for (int b = 0; b < 8; ++b) xa[b] = xp[b * D_BLADE];

    float geo[8] = {0.f,0.f,0.f,0.f,0.f,0.f,0.f,0.f};
#pragma unroll
    for (int p = 0; p < 64; ++p)
        geo[CK[p]] += coefs[p] * xa[p >> 3] * xa[p & 7];

    const float g = sigm(gg[0]);
    float mixed[8], sm[8], sq[8];
#pragma unroll
    for (int b = 0; b < 8; ++b) {
        mixed[b] = g * geo[b] + (1.0f - g) * xa[b];
        sm[b] = mixed[b];
        sq[b] = mixed[b] * mixed[b];
    }
#pragma unroll
    for (int off = 32; off > 0; off >>= 1) {
#pragma unroll
        for (int b = 0; b < 8; ++b) {
            sm[b] += __shfl_xor(sm[b], off, 64);
            sq[b] += __shfl_xor(sq[b], off, 64);
        }
    }
    const int wv = tid >> 6;
    if ((tid & 63) == 0) {
#pragma unroll
        for (int b = 0; b < 8; ++b) { redA[wv][b] = sm[b]; redB[wv][b] = sq[b]; }
    }
    __syncthreads();

    const float lw = lnw[tid], lb = lnb[tid];
    __hip_bfloat16* op = nrm + ((size_t)n * 8) * D_BLADE + tid;
#pragma unroll
    for (int b = 0; b < 8; ++b) {
        float ts = redA[0][b] + redA[1][b] + redA[2][b] + redA[3][b];
        float tq = redB[0][b] + redB[1][b] + redB[2][b] + redB[3][b];
        float mu = ts * (1.0f / 256.0f);
        float var = tq * (1.0f / 256.0f) - mu * mu;
        float rs = rsqrtf(var + 1e-5f);
        op[b * D_BLADE] = __float2bfloat16((mixed[b] - mu) * rs * lw + lb);
    }
}

// ---------------- fused SwiGLU FFN + residual ----------------
// BM=64, 256 threads = 4 waves, LDS 48KB -> 3 blocks/CU (12 waves/CU = 3/SIMD).
// VGPR capped at 128 via __launch_bounds__(256,4) so 12 waves fit.
// Chunking: FC=64. Wave w: p2 computes full M=64 x F=16 (w*16) gate+up;
// p3 computes full M=64 x N=64 (w*64). Weights read once per block (dup=1).
// sN/sH XOR-swizzled (byte ^= (row&7)<<4). sH double-buffered, 1 barrier/chunk.
__global__ __launch_bounds__(256, 4) void ffn_kernel(
    const __hip_bfloat16* __restrict__ nrm,
    const __hip_bfloat16* __restrict__ gw,
    const __hip_bfloat16* __restrict__ uw,
    const __hip_bfloat16* __restrict__ dw,
    const float* __restrict__ x,
    float* __restrict__ out)
{
    extern __shared__ char lds[];
    char* sN = lds;                    // [64][512B] swizzled
    char* sH = lds + SN_BYTES;         // [2][64][128B] swizzled

    const int tid = threadIdx.x;
    const int l = tid & 63;
    const int w = tid >> 6;       // wave 0..3
    const int rr = l & 15;
    const int kq = l >> 4;        // 0..3
    const int rsw = (rr & 7) << 4;  // swizzle for A-frag rows (row%8 == rr%8)
    const int m0 = blockIdx.x * BM;

    // stage normed 64x256 bf16 tile: linear LDS dest, inverse-swizzled global col
#pragma unroll
    for (int i = 0; i < 8; ++i) {
        int L = (i * 256 + tid) * 16;          // linear byte 0..32767
        int r = L >> 9;
        int X = L & 511;
        int gcol = (X ^ ((r & 7) << 4)) >> 1;
        bf16x8 v = *reinterpret_cast<const bf16x8*>(nrm + (size_t)(m0 + r) * D_BLADE + gcol);
        *reinterpret_cast<bf16x8*>(sN + r * 512 + X) = v;
    }

    const f32x4 zero = {0.f, 0.f, 0.f, 0.f};
    f32x4 acc[4][4];                  // 64 VGPR: M=64 x N=64 per wave
#pragma unroll
    for (int mt = 0; mt < 4; ++mt)
#pragma unroll
        for (int nt = 0; nt < 4; ++nt) acc[mt][nt] = zero;
    f32x4 hg[4], hu[4];               // 32 VGPR

    // ---- phase2: gate/up for chunk fc; wave's F=16 slice, full M=64 ----
    auto p2compute = [&](int fc) {
#pragma unroll
        for (int mt = 0; mt < 4; ++mt) { hg[mt] = zero; hu[mt] = zero; }
        const __hip_bfloat16* gR = gw + (size_t)(fc * FC + w * 16 + rr) * D_BLADE + kq * 8;
        const __hip_bfloat16* uR = uw + (size_t)(fc * FC + w * 16 + rr) * D_BLADE + kq * 8;
#pragma unroll
        for (int kk = 0; kk < 8; ++kk) {
            bf16x8 bg = *reinterpret_cast<const bf16x8*>(gR + kk * 32);
            bf16x8 bu = *reinterpret_cast<const bf16x8*>(uR + kk * 32);
            const int cb = (kk * 64 + kq * 16) ^ rsw;
            __builtin_amdgcn_s_setprio(1);
#pragma unroll
            for (int mt = 0; mt < 4; ++mt) {
                bf16x8 a = *reinterpret_cast<const bf16x8*>(sN + (mt * 16 + rr) * 512 + cb);
                hg[mt] = __builtin_amdgcn_mfma_f32_16x16x32_bf16(a, bg, hg[mt], 0, 0, 0);
                hu[mt] = __builtin_amdgcn_mfma_f32_16x16x32_bf16(a, bu, hu[mt], 0, 0, 0);
            }
            __builtin_amdgcn_s_setprio(0);
        }
    };

    // ---- silu(g)*u -> sH[buf]: pair-pack cols via shfl_xor(1), swizzled b32 writes ----
    auto writeH = [&](int c) {
        char* buf = sH + (c & 1) * SH_BYTES;
        const int p = rr & 1;
        const int colb = (w * 16 + (rr & ~1)) * 2;
#pragma unroll
        for (int mt = 0; mt < 4; ++mt) {
            float g0 = hg[mt][0], g1 = hg[mt][1], g2 = hg[mt][2], g3 = hg[mt][3];
            float h0 = g0 * sigm(g0) * hu[mt][0];
            float h1 = g1 * sigm(g1) * hu[mt][1];
            float h2 = g2 * sigm(g2) * hu[mt][2];
            float h3 = g3 * sigm(g3) * hu[mt][3];
#pragma unroll
            for (int j = 0; j < 2; ++j) {
                float own  = p ? (j ? h3 : h2) : (j ? h1 : h0);
                float sent = p ? (j ? h1 : h0) : (j ? h3 : h2);
                float recv = __shfl_xor(sent, 1, 64);
                float lo = p ? recv : own;
                float hi = p ? own : recv;
                __hip_bfloat162 pk;
                pk.x = __float2bfloat16(lo);
                pk.y = __float2bfloat16(hi);
                int row = mt * 16 + kq * 4 + p * 2 + j;
                *reinterpret_cast<__hip_bfloat162*>(buf + row * 128 + (colb ^ ((row & 7) << 4))) = pk;
            }
        }
    };

    // ---- phase3: down-GEMM partials; wave's N=64 slice, full M=64, K=FC=64 ----
    auto p3 = [&](int c) {
        const char* buf = sH + (c & 1) * SH_BYTES;
        const __hip_bfloat16* dR = dw + (size_t)(w * 64 + rr) * D_FFN + c * FC + kq * 8;
#pragma unroll
        for (int kk = 0; kk < 2; ++kk) {
            bf16x8 b0 = *reinterpret_cast<const bf16x8*>(dR + kk * 32);
            bf16x8 b1 = *reinterpret_cast<const bf16x8*>(dR + 16 * D_FFN + kk * 32);
            bf16x8 b2 = *reinterpret_cast<const bf16x8*>(dR + 32 * D_FFN + kk * 32);
            bf16x8 b3 = *reinterpret_cast<const bf16x8*>(dR + 48 * D_FFN + kk * 32);
            const int cb = (kk * 64 + kq * 16) ^ rsw;
            __builtin_amdgcn_s_setprio(1);
#pragma unroll
            for (int mt = 0; mt < 4; ++mt) {
                bf16x8 a = *reinterpret_cast<const bf16x8*>(buf + (mt * 16 + rr) * 128 + cb);
                acc[mt][0] = __builtin_amdgcn_mfma_f32_16x16x32_bf16(a, b0, acc[mt][0], 0, 0, 0);
                acc[mt][1] = __builtin_amdgcn_mfma_f32_16x16x32_bf16(a, b1, acc[mt][1], 0, 0, 0);
                acc[mt][2] = __builtin_amdgcn_mfma_f32_16x16x32_bf16(a, b2, acc[mt][2], 0, 0, 0);
                acc[mt][3] = __builtin_amdgcn_mfma_f32_16x16x32_bf16(a, b3, acc[mt][3], 0, 0, 0);
            }
            __builtin_amdgcn_s_setprio(0);
        }
    };

    __syncthreads();            // sN staged
    p2compute(0);
    writeH(0);
    __syncthreads();            // sH(0) ready
    for (int c = 0; c < 16; ++c) {
        p3(c);                               // reads buf[c&1]
        if (c < 15) { p2compute(c + 1); writeH(c + 1); }  // writes buf[(c+1)&1]
        __syncthreads();
    }

    // epilogue: residual add, f32 store
#pragma unroll
    for (int mt = 0; mt < 4; ++mt)
#pragma unroll
        for (int nt = 0; nt < 4; ++nt)
#pragma unroll
            for (int r = 0; r < 4; ++r) {
                int m = m0 + mt * 16 + kq * 4 + r;
                int d = w * 64 + nt * 16 + rr;
                size_t idx = (size_t)m * D_BLADE + d;
                out[idx] = x[idx] + acc[mt][nt][r];
            }
}

extern "C" void kernel_launch(void* const* d_in, const int* in_sizes, int n_in,
                              void* d_out, int out_size, void* d_ws, size_t ws_size,
                              hipStream_t stream) {
    const float* x   = (const float*)d_in[0];
    const float* iw  = (const float*)d_in[1];
    const float* sg  = (const float*)d_in[2];
    const float* gg  = (const float*)d_in[3];
    const float* gwf = (const float*)d_in[4];
    const float* uwf = (const float*)d_in[5];
    const float* dwf = (const float*)d_in[6];
    const float* lnw = (const float*)d_in[7];
    const float* lnb = (const float*)d_in[8];
    float* out = (float*)d_out;

    char* ws = (char*)d_ws;
    __hip_bfloat16* nrm = (__hip_bfloat16*)ws;
    __hip_bfloat16* gb  = (__hip_bfloat16*)(ws + (size_t)M_TOTAL * D_BLADE * 2);
    __hip_bfloat16* ub  = gb + (size_t)D_FFN * D_BLADE;
    __hip_bfloat16* db  = ub + (size_t)D_FFN * D_BLADE;

    wconv_kernel<<<dim3((D_FFN * D_BLADE) / 256), dim3(256), 0, stream>>>(gwf, uwf, dwf, gb, ub, db);
    geo_ln_kernel<<<dim3(N_TOK), dim3(256), 0, stream>>>(x, iw, sg, gg, lnw, lnb, nrm);
    ffn_kernel<<<dim3(M_TOTAL / BM), dim3(256), LDS_BYTES, stream>>>(nrm, gb, ub, db, x, out);
}

// Round 6
// 207.417 us; speedup vs baseline: 1.5439x; 1.5439x over previous
//
#include <hip/hip_runtime.h>
#include <hip/hip_bf16.h>

#define D_BLADE 256
#define D_FFN 1024
#define N_TOK 8192
#define M_TOTAL (N_TOK * 8)

typedef __attribute__((ext_vector_type(8))) short bf16x8;
typedef __attribute__((ext_vector_type(4))) float f32x4;
typedef __attribute__((address_space(1))) void gvoid;
typedef __attribute__((address_space(3))) void svoid;

__device__ __forceinline__ float sigm(float v) { return 1.0f / (1.0f + __expf(-v)); }

// ---------------- weight pack: fp32 -> bf16, gate/up interleaved by 16 rows ----------------
// wgu row layout (2048 rows x 256): rows t*32+0..15 = gate f=t*16..t*16+15,
// rows t*32+16..31 = up (same f). An MFMA 16-col tile is then pure gate or pure up,
// and (gate,up) for one f sit in the SAME lane across adjacent nt tiles.
__global__ __launch_bounds__(256) void wconv_kernel(const float* __restrict__ g,
                                                    const float* __restrict__ u,
                                                    const float* __restrict__ dn,
                                                    __hip_bfloat16* __restrict__ wgu,
                                                    __hip_bfloat16* __restrict__ dwb) {
    int i = blockIdx.x * 256 + threadIdx.x;   // 262144 elems
    int f = i >> 8, k = i & 255;
    int t = f >> 4, fi = f & 15;
    wgu[(size_t)(t * 32 + fi) * 256 + k]      = __float2bfloat16(g[i]);
    wgu[(size_t)(t * 32 + 16 + fi) * 256 + k] = __float2bfloat16(u[i]);
    dwb[i] = __float2bfloat16(dn[i]);
}

// ---------------- geometric product + mix + LayerNorm -> normed (bf16) ----------------
__global__ __launch_bounds__(256) void geo_ln_kernel(
    const float* __restrict__ x, const float* __restrict__ iw,
    const float* __restrict__ sg, const float* __restrict__ gg,
    const float* __restrict__ lnw, const float* __restrict__ lnb,
    __hip_bfloat16* __restrict__ nrm)
{
    static constexpr int CK[64] = {
        0,1,2,3,4,5,6,7,
        1,0,4,5,2,3,7,6,
        2,4,0,6,1,7,3,5,
        3,5,6,0,7,1,2,4,
        4,2,1,7,0,6,5,3,
        5,3,7,1,6,0,4,2,
        6,7,3,2,5,4,0,1,
        7,6,5,4,3,2,1,0};
    __shared__ float coefs[64];
    __shared__ float redA[4][8];
    __shared__ float redB[4][8];
    const int tid = threadIdx.x;
    const int n = blockIdx.x;
    if (tid < 64) coefs[tid] = sg[tid] * sigm(iw[tid]);
    __syncthreads();

    const float* xp = x + (size_t)n * (8 * D_BLADE) + tid;
    float xa[8];
#pragma unroll
    for (int b = 0; b < 8; ++b) xa[b] = xp[b * D_BLADE];

    float geo[8] = {0.f,0.f,0.f,0.f,0.f,0.f,0.f,0.f};
#pragma unroll
    for (int p = 0; p < 64; ++p)
        geo[CK[p]] += coefs[p] * xa[p >> 3] * xa[p & 7];

    const float g = sigm(gg[0]);
    float mixed[8], sm[8], sq[8];
#pragma unroll
    for (int b = 0; b < 8; ++b) {
        mixed[b] = g * geo[b] + (1.0f - g) * xa[b];
        sm[b] = mixed[b];
        sq[b] = mixed[b] * mixed[b];
    }
#pragma unroll
    for (int off = 32; off > 0; off >>= 1) {
#pragma unroll
        for (int b = 0; b < 8; ++b) {
            sm[b] += __shfl_xor(sm[b], off, 64);
            sq[b] += __shfl_xor(sq[b], off, 64);
        }
    }
    const int wv = tid >> 6;
    if ((tid & 63) == 0) {
#pragma unroll
        for (int b = 0; b < 8; ++b) { redA[wv][b] = sm[b]; redB[wv][b] = sq[b]; }
    }
    __syncthreads();

    const float lw = lnw[tid], lb = lnb[tid];
    __hip_bfloat16* op = nrm + ((size_t)n * 8) * D_BLADE + tid;
#pragma unroll
    for (int b = 0; b < 8; ++b) {
        float ts = redA[0][b] + redA[1][b] + redA[2][b] + redA[3][b];
        float tq = redB[0][b] + redB[1][b] + redB[2][b] + redB[3][b];
        float mu = ts * (1.0f / 256.0f);
        float var = tq * (1.0f / 256.0f) - mu * mu;
        float rs = rsqrtf(var + 1e-5f);
        op[b * D_BLADE] = __float2bfloat16((mixed[b] - mu) * rs * lw + lb);
    }
}

// ============ m97-style GEMM building blocks ============
// Tile 128x128, BK=64, 256 threads / 4 waves (2x2), wave tile 64x64, acc 4x4.
// LDS: sA[128][64] + sB[128][64] bf16 (16KB each), single-buffered.
// Swizzle: byte-in-row X stored at X ^ ((row&7)<<4); staged via global_load_lds
// width=16 with inverse-swizzled per-lane GLOBAL source (rule 21: linear dest).
// ds_read_b128: 64 lanes -> uniform 8 lanes per 16B slot = LDS throughput floor.

#define STAGE_TILE(dst, srcbase, rowstride, kofs)                                   \
    _Pragma("unroll")                                                                \
    for (int i = 0; i < 4; ++i) {                                                    \
        int L = i * 4096 + tid * 16;                                                 \
        int r = L >> 7;                                                              \
        int Xs = (L & 127) ^ ((r & 7) << 4);                                         \
        const __hip_bfloat16* sp = (srcbase) + (size_t)(r) * (rowstride) + (kofs) + (Xs >> 1); \
        __builtin_amdgcn_global_load_lds((gvoid*)sp, (svoid*)((dst) + L), 16, 0, 0); \
    }

// ---------------- gate/up GEMM + silu*mul epilogue -> h ----------------
__global__ __launch_bounds__(256, 4) void gu_kernel(
    const __hip_bfloat16* __restrict__ nrm,
    const __hip_bfloat16* __restrict__ wgu,
    __hip_bfloat16* __restrict__ h,
    int mbase)
{
    __shared__ char lds[32768];
    char* sA = lds;
    char* sB = lds + 16384;

    const int tid = threadIdx.x;
    const int l = tid & 63;
    const int w = tid >> 6;
    const int wm = w >> 1, wn = w & 1;
    const int rr = l & 15;
    const int kq = l >> 4;
    const int bm = blockIdx.x >> 4;
    const int n0 = (blockIdx.x & 15) * 128;
    const int m0 = mbase + bm * 128;       // global row into nrm
    const int hr0 = bm * 128;              // local row into h (per split)
    const __hip_bfloat16* An = nrm + (size_t)m0 * D_BLADE;
    const __hip_bfloat16* Bn = wgu + (size_t)n0 * D_BLADE;

    const f32x4 zero = {0.f, 0.f, 0.f, 0.f};
    f32x4 acc[4][4];
#pragma unroll
    for (int mt = 0; mt < 4; ++mt)
#pragma unroll
        for (int nt = 0; nt < 4; ++nt) acc[mt][nt] = zero;

    const int rsw = (rr & 7) << 4;

    STAGE_TILE(sA, An, D_BLADE, 0)
    STAGE_TILE(sB, Bn, D_BLADE, 0)
    asm volatile("s_waitcnt vmcnt(0)" ::: "memory");
    __syncthreads();

    for (int c = 0; c < 4; ++c) {
#pragma unroll
        for (int kk = 0; kk < 2; ++kk) {
            const int cb = (kk * 64 + kq * 16) ^ rsw;
            bf16x8 a[4], b[4];
#pragma unroll
            for (int nt = 0; nt < 4; ++nt)
                b[nt] = *reinterpret_cast<const bf16x8*>(sB + (wn * 64 + nt * 16 + rr) * 128 + cb);
#pragma unroll
            for (int mt = 0; mt < 4; ++mt)
                a[mt] = *reinterpret_cast<const bf16x8*>(sA + (wm * 64 + mt * 16 + rr) * 128 + cb);
            __builtin_amdgcn_s_setprio(1);
#pragma unroll
            for (int mt = 0; mt < 4; ++mt)
#pragma unroll
                for (int nt = 0; nt < 4; ++nt)
                    acc[mt][nt] = __builtin_amdgcn_mfma_f32_16x16x32_bf16(a[mt], b[nt], acc[mt][nt], 0, 0, 0);
            __builtin_amdgcn_s_setprio(0);
        }
        __syncthreads();                   // reads of this step done
        if (c < 3) {
            STAGE_TILE(sA, An, D_BLADE, (c + 1) * 64)
            STAGE_TILE(sB, Bn, D_BLADE, (c + 1) * 64)
            asm volatile("s_waitcnt vmcnt(0)" ::: "memory");
            __syncthreads();               // new tile visible
        }
    }

    // epilogue: nt even = gate tile, nt odd = up tile (same f, same lane)
#pragma unroll
    for (int mt = 0; mt < 4; ++mt)
#pragma unroll
        for (int ntp = 0; ntp < 2; ++ntp) {
            f32x4 gv = acc[mt][2 * ntp];
            f32x4 uv = acc[mt][2 * ntp + 1];
            const int fcol = ((n0 + wn * 64) >> 1) + ntp * 16 + rr;
#pragma unroll
            for (int r = 0; r < 4; ++r) {
                int row = hr0 + wm * 64 + mt * 16 + kq * 4 + r;
                float ge = gv[r];
                float hv = ge * sigm(ge) * uv[r];
                h[(size_t)row * D_FFN + fcol] = __float2bfloat16(hv);
            }
        }
}

// ---------------- down GEMM + residual -> out ----------------
__global__ __launch_bounds__(256, 4) void down_kernel(
    const __hip_bfloat16* __restrict__ h,
    const __hip_bfloat16* __restrict__ dwb,
    const float* __restrict__ x,
    float* __restrict__ out,
    int mbase)
{
    __shared__ char lds[32768];
    char* sA = lds;
    char* sB = lds + 16384;

    const int tid = threadIdx.x;
    const int l = tid & 63;
    const int w = tid >> 6;
    const int wm = w >> 1, wn = w & 1;
    const int rr = l & 15;
    const int kq = l >> 4;
    const int bm = blockIdx.x >> 1;
    const int n0 = (blockIdx.x & 1) * 128;
    const int hr0 = bm * 128;              // local rows into h
    const __hip_bfloat16* An = h + (size_t)hr0 * D_FFN;
    const __hip_bfloat16* Bn = dwb + (size_t)n0 * D_FFN;

    const f32x4 zero = {0.f, 0.f, 0.f, 0.f};
    f32x4 acc[4][4];
#pragma unroll
    for (int mt = 0; mt < 4; ++mt)
#pragma unroll
        for (int nt = 0; nt < 4; ++nt) acc[mt][nt] = zero;

    const int rsw = (rr & 7) << 4;

    STAGE_TILE(sA, An, D_FFN, 0)
    STAGE_TILE(sB, Bn, D_FFN, 0)
    asm volatile("s_waitcnt vmcnt(0)" ::: "memory");
    __syncthreads();

    for (int c = 0; c < 16; ++c) {
#pragma unroll
        for (int kk = 0; kk < 2; ++kk) {
            const int cb = (kk * 64 + kq * 16) ^ rsw;
            bf16x8 a[4], b[4];
#pragma unroll
            for (int nt = 0; nt < 4; ++nt)
                b[nt] = *reinterpret_cast<const bf16x8*>(sB + (wn * 64 + nt * 16 + rr) * 128 + cb);
#pragma unroll
            for (int mt = 0; mt < 4; ++mt)
                a[mt] = *reinterpret_cast<const bf16x8*>(sA + (wm * 64 + mt * 16 + rr) * 128 + cb);
            __builtin_amdgcn_s_setprio(1);
#pragma unroll
            for (int mt = 0; mt < 4; ++mt)
#pragma unroll
                for (int nt = 0; nt < 4; ++nt)
                    acc[mt][nt] = __builtin_amdgcn_mfma_f32_16x16x32_bf16(a[mt], b[nt], acc[mt][nt], 0, 0, 0);
            __builtin_amdgcn_s_setprio(0);
        }
        __syncthreads();
        if (c < 15) {
            STAGE_TILE(sA, An, D_FFN, (c + 1) * 64)
            STAGE_TILE(sB, Bn, D_FFN, (c + 1) * 64)
            asm volatile("s_waitcnt vmcnt(0)" ::: "memory");
            __syncthreads();
        }
    }

    // epilogue: residual add, f32 store
#pragma unroll
    for (int mt = 0; mt < 4; ++mt)
#pragma unroll
        for (int nt = 0; nt < 4; ++nt)
#pragma unroll
            for (int r = 0; r < 4; ++r) {
                int gm = mbase + hr0 + wm * 64 + mt * 16 + kq * 4 + r;
                int d = n0 + wn * 64 + nt * 16 + rr;
                size_t idx = (size_t)gm * D_BLADE + d;
                out[idx] = x[idx] + acc[mt][nt][r];
            }
}

extern "C" void kernel_launch(void* const* d_in, const int* in_sizes, int n_in,
                              void* d_out, int out_size, void* d_ws, size_t ws_size,
                              hipStream_t stream) {
    const float* x   = (const float*)d_in[0];
    const float* iw  = (const float*)d_in[1];
    const float* sg  = (const float*)d_in[2];
    const float* gg  = (const float*)d_in[3];
    const float* gwf = (const float*)d_in[4];
    const float* uwf = (const float*)d_in[5];
    const float* dwf = (const float*)d_in[6];
    const float* lnw = (const float*)d_in[7];
    const float* lnb = (const float*)d_in[8];
    float* out = (float*)d_out;

    char* ws = (char*)d_ws;
    __hip_bfloat16* nrm = (__hip_bfloat16*)ws;                       // 33.5 MB
    size_t off = (size_t)M_TOTAL * D_BLADE * 2;
    __hip_bfloat16* wgu = (__hip_bfloat16*)(ws + off);               // 1 MB
    off += (size_t)2 * D_FFN * D_BLADE * 2;
    __hip_bfloat16* dwb = (__hip_bfloat16*)(ws + off);               // 0.5 MB
    off += (size_t)D_FFN * D_BLADE * 2;
    __hip_bfloat16* h = (__hip_bfloat16*)(ws + off);                 // MS*2048 B per split

    // choose smallest split count S (power of 2) whose h-chunk fits in ws
    int S = 1;
    while (S < 64 && off + ((size_t)M_TOTAL / S) * D_FFN * 2 > ws_size) S <<= 1;
    const int MS = M_TOTAL / S;

    wconv_kernel<<<dim3((D_FFN * D_BLADE) / 256), dim3(256), 0, stream>>>(gwf, uwf, dwf, wgu, dwb);
    geo_ln_kernel<<<dim3(N_TOK), dim3(256), 0, stream>>>(x, iw, sg, gg, lnw, lnb, nrm);
    for (int s = 0; s < S; ++s) {
        gu_kernel<<<dim3((MS / 128) * 16), dim3(256), 0, stream>>>(nrm, wgu, h, s * MS);
        down_kernel<<<dim3((MS / 128) * 2), dim3(256), 0, stream>>>(h, dwb, x, out, s * MS);
    }
}

// Round 8
// 200.333 us; speedup vs baseline: 1.5985x; 1.0354x over previous
//
#include <hip/hip_runtime.h>
#include <hip/hip_bf16.h>

#define D_BLADE 256
#define D_FFN 1024
#define N_TOK 8192
#define M_TOTAL (N_TOK * 8)

typedef __attribute__((ext_vector_type(8))) short bf16x8;
typedef __attribute__((ext_vector_type(4))) float f32x4;
typedef __attribute__((address_space(1))) void gvoid;
typedef __attribute__((address_space(3))) void svoid;

__device__ __forceinline__ float sigm(float v) { return 1.0f / (1.0f + __expf(-v)); }

// ---------------- weight pack: fp32 -> bf16, gate/up interleaved by 16 rows ----------------
// wgu (2048 rows x 256): rows t*32+0..15 = gate f=t*16..+15, rows t*32+16..31 = up (same f).
__global__ __launch_bounds__(256) void wconv_kernel(const float* __restrict__ g,
                                                    const float* __restrict__ u,
                                                    const float* __restrict__ dn,
                                                    __hip_bfloat16* __restrict__ wgu,
                                                    __hip_bfloat16* __restrict__ dwb) {
    int i = blockIdx.x * 256 + threadIdx.x;   // 262144 elems
    int f = i >> 8, k = i & 255;
    int t = f >> 4, fi = f & 15;
    wgu[(size_t)(t * 32 + fi) * 256 + k]      = __float2bfloat16(g[i]);
    wgu[(size_t)(t * 32 + 16 + fi) * 256 + k] = __float2bfloat16(u[i]);
    dwb[i] = __float2bfloat16(dn[i]);
}

// ---------------- geometric product + mix + LayerNorm -> normed (bf16) ----------------
__global__ __launch_bounds__(256) void geo_ln_kernel(
    const float* __restrict__ x, const float* __restrict__ iw,
    const float* __restrict__ sg, const float* __restrict__ gg,
    const float* __restrict__ lnw, const float* __restrict__ lnb,
    __hip_bfloat16* __restrict__ nrm)
{
    static constexpr int CK[64] = {
        0,1,2,3,4,5,6,7,
        1,0,4,5,2,3,7,6,
        2,4,0,6,1,7,3,5,
        3,5,6,0,7,1,2,4,
        4,2,1,7,0,6,5,3,
        5,3,7,1,6,0,4,2,
        6,7,3,2,5,4,0,1,
        7,6,5,4,3,2,1,0};
    __shared__ float coefs[64];
    __shared__ float redA[4][8];
    __shared__ float redB[4][8];
    const int tid = threadIdx.x;
    const int n = blockIdx.x;
    if (tid < 64) coefs[tid] = sg[tid] * sigm(iw[tid]);
    __syncthreads();

    const float* xp = x + (size_t)n * (8 * D_BLADE) + tid;
    float xa[8];
#pragma unroll
    for (int b = 0; b < 8; ++b) xa[b] = xp[b * D_BLADE];

    float geo[8] = {0.f,0.f,0.f,0.f,0.f,0.f,0.f,0.f};
#pragma unroll
    for (int p = 0; p < 64; ++p)
        geo[CK[p]] += coefs[p] * xa[p >> 3] * xa[p & 7];

    const float g = sigm(gg[0]);
    float mixed[8], sm[8], sq[8];
#pragma unroll
    for (int b = 0; b < 8; ++b) {
        mixed[b] = g * geo[b] + (1.0f - g) * xa[b];
        sm[b] = mixed[b];
        sq[b] = mixed[b] * mixed[b];
    }
#pragma unroll
    for (int off = 32; off > 0; off >>= 1) {
#pragma unroll
        for (int b = 0; b < 8; ++b) {
            sm[b] += __shfl_xor(sm[b], off, 64);
            sq[b] += __shfl_xor(sq[b], off, 64);
        }
    }
    const int wv = tid >> 6;
    if ((tid & 63) == 0) {
#pragma unroll
        for (int b = 0; b < 8; ++b) { redA[wv][b] = sm[b]; redB[wv][b] = sq[b]; }
    }
    __syncthreads();

    const float lw = lnw[tid], lb = lnb[tid];
    __hip_bfloat16* op = nrm + ((size_t)n * 8) * D_BLADE + tid;
#pragma unroll
    for (int b = 0; b < 8; ++b) {
        float ts = redA[0][b] + redA[1][b] + redA[2][b] + redA[3][b];
        float tq = redB[0][b] + redB[1][b] + redB[2][b] + redB[3][b];
        float mu = ts * (1.0f / 256.0f);
        float var = tq * (1.0f / 256.0f) - mu * mu;
        float rs = rsqrtf(var + 1e-5f);
        op[b * D_BLADE] = __float2bfloat16((mixed[b] - mu) * rs * lw + lb);
    }
}

// ============ GEMM building blocks ============
// XOR-swizzle byte X -> X ^ ((row&7)<<4); staged linear via global_load_lds w=16 with
// inverse-swizzled global source (verified R6: conflicts = 0).

#define STAGE(dst, srcbase, rowstride, kofs, NLOADS)                                 \
    _Pragma("unroll")                                                                 \
    for (int i = 0; i < (NLOADS); ++i) {                                              \
        int L = i * 4096 + tid * 16;                                                  \
        int r = L >> 7;                                                               \
        int Xs = (L & 127) ^ ((r & 7) << 4);                                          \
        const __hip_bfloat16* sp = (srcbase) + (size_t)(r) * (rowstride) + (kofs) + (Xs >> 1); \
        __builtin_amdgcn_global_load_lds((gvoid*)sp, (svoid*)((dst) + L), 16, 0, 0);  \
    }

// ---------------- gate/up GEMM + silu*mul epilogue -> h  (EXACT round-6 version) ----------------
// Tile 128x128, BK=64, 4 waves (2x2), wave tile 64x64, acc 4x4, LDS 32KB, 4 blocks/CU.
__global__ __launch_bounds__(256, 4) void gu_kernel(
    const __hip_bfloat16* __restrict__ nrm,
    const __hip_bfloat16* __restrict__ wgu,
    __hip_bfloat16* __restrict__ h,
    int mbase)
{
    __shared__ char lds[32768];
    char* sA = lds;
    char* sB = lds + 16384;

    const int tid = threadIdx.x;
    const int l = tid & 63;
    const int w = tid >> 6;
    const int wm = w >> 1, wn = w & 1;
    const int rr = l & 15;
    const int kq = l >> 4;
    const int bm = blockIdx.x >> 4;
    const int n0 = (blockIdx.x & 15) * 128;
    const int m0 = mbase + bm * 128;       // global row into nrm
    const int hr0 = bm * 128;              // local row into h (per split)
    const __hip_bfloat16* An = nrm + (size_t)m0 * D_BLADE;
    const __hip_bfloat16* Bn = wgu + (size_t)n0 * D_BLADE;

    const f32x4 zero = {0.f, 0.f, 0.f, 0.f};
    f32x4 acc[4][4];
#pragma unroll
    for (int mt = 0; mt < 4; ++mt)
#pragma unroll
        for (int nt = 0; nt < 4; ++nt) acc[mt][nt] = zero;

    const int rsw = (rr & 7) << 4;

    STAGE(sA, An, D_BLADE, 0, 4)
    STAGE(sB, Bn, D_BLADE, 0, 4)
    asm volatile("s_waitcnt vmcnt(0)" ::: "memory");
    __syncthreads();

    for (int c = 0; c < 4; ++c) {
#pragma unroll
        for (int kk = 0; kk < 2; ++kk) {
            const int cb = (kk * 64 + kq * 16) ^ rsw;
            bf16x8 a[4], b[4];
#pragma unroll
            for (int nt = 0; nt < 4; ++nt)
                b[nt] = *reinterpret_cast<const bf16x8*>(sB + (wn * 64 + nt * 16 + rr) * 128 + cb);
#pragma unroll
            for (int mt = 0; mt < 4; ++mt)
                a[mt] = *reinterpret_cast<const bf16x8*>(sA + (wm * 64 + mt * 16 + rr) * 128 + cb);
            __builtin_amdgcn_s_setprio(1);
#pragma unroll
            for (int mt = 0; mt < 4; ++mt)
#pragma unroll
                for (int nt = 0; nt < 4; ++nt)
                    acc[mt][nt] = __builtin_amdgcn_mfma_f32_16x16x32_bf16(a[mt], b[nt], acc[mt][nt], 0, 0, 0);
            __builtin_amdgcn_s_setprio(0);
        }
        __syncthreads();                   // reads of this step done
        if (c < 3) {
            STAGE(sA, An, D_BLADE, (c + 1) * 64, 4)
            STAGE(sB, Bn, D_BLADE, (c + 1) * 64, 4)
            asm volatile("s_waitcnt vmcnt(0)" ::: "memory");
            __syncthreads();               // new tile visible
        }
    }

    // epilogue: nt even = gate tile, nt odd = up tile (same f, same lane)
#pragma unroll
    for (int mt = 0; mt < 4; ++mt)
#pragma unroll
        for (int ntp = 0; ntp < 2; ++ntp) {
            f32x4 gv = acc[mt][2 * ntp];
            f32x4 uv = acc[mt][2 * ntp + 1];
            const int fcol = ((n0 + wn * 64) >> 1) + ntp * 16 + rr;
#pragma unroll
            for (int r = 0; r < 4; ++r) {
                int row = hr0 + wm * 64 + mt * 16 + kq * 4 + r;
                float ge = gv[r];
                float hv = ge * sigm(ge) * uv[r];
                h[(size_t)row * D_FFN + fcol] = __float2bfloat16(hv);
            }
        }
}

// ---------------- down GEMM + residual -> out (full N=256 per block) ----------------
// Tile 128x256, acc 4x8, LDS 48KB, 2 blocks/CU. h read exactly once.
__global__ __launch_bounds__(256, 2) void down_kernel(
    const __hip_bfloat16* __restrict__ h,
    const __hip_bfloat16* __restrict__ dwb,
    const float* __restrict__ x,
    float* __restrict__ out,
    int mbase)
{
    __shared__ char lds[49152];
    char* sA = lds;            // h tile [128][128B]
    char* sB = lds + 16384;    // dw tile [256][128B]

    const int tid = threadIdx.x;
    const int l = tid & 63;
    const int w = tid >> 6;
    const int wm = w >> 1, wn = w & 1;
    const int rr = l & 15;
    const int kq = l >> 4;
    const int rsw = (rr & 7) << 4;
    const int bm = blockIdx.x;
    const int hr0 = bm * 128;
    const __hip_bfloat16* An = h + (size_t)hr0 * D_FFN;
    const __hip_bfloat16* Bn = dwb;

    const f32x4 zero = {0.f, 0.f, 0.f, 0.f};
    f32x4 acc[4][8];
#pragma unroll
    for (int mt = 0; mt < 4; ++mt)
#pragma unroll
        for (int nt = 0; nt < 8; ++nt) acc[mt][nt] = zero;

    STAGE(sA, An, D_FFN, 0, 4)
    STAGE(sB, Bn, D_FFN, 0, 8)
    asm volatile("s_waitcnt vmcnt(0)" ::: "memory");
    __builtin_amdgcn_sched_barrier(0);
    __syncthreads();

    for (int c = 0; c < 16; ++c) {
#pragma unroll
        for (int kk = 0; kk < 2; ++kk) {
            const int cb = (kk * 64 + kq * 16) ^ rsw;
            bf16x8 a[4], b[8];
#pragma unroll
            for (int nt = 0; nt < 8; ++nt)
                b[nt] = *reinterpret_cast<const bf16x8*>(sB + (wn * 128 + nt * 16 + rr) * 128 + cb);
#pragma unroll
            for (int mt = 0; mt < 4; ++mt)
                a[mt] = *reinterpret_cast<const bf16x8*>(sA + (wm * 64 + mt * 16 + rr) * 128 + cb);
            __builtin_amdgcn_s_setprio(1);
#pragma unroll
            for (int mt = 0; mt < 4; ++mt)
#pragma unroll
                for (int nt = 0; nt < 8; ++nt)
                    acc[mt][nt] = __builtin_amdgcn_mfma_f32_16x16x32_bf16(a[mt], b[nt], acc[mt][nt], 0, 0, 0);
            __builtin_amdgcn_s_setprio(0);
        }
        __syncthreads();
        if (c < 15) {
            STAGE(sA, An, D_FFN, (c + 1) * 64, 4)
            STAGE(sB, Bn, D_FFN, (c + 1) * 64, 8)
            asm volatile("s_waitcnt vmcnt(0)" ::: "memory");
            __builtin_amdgcn_sched_barrier(0);
            __syncthreads();
        }
    }

    // epilogue: residual add, f32 store
#pragma unroll
    for (int mt = 0; mt < 4; ++mt)
#pragma unroll
        for (int nt = 0; nt < 8; ++nt)
#pragma unroll
            for (int r = 0; r < 4; ++r) {
                int gm = mbase + hr0 + wm * 64 + mt * 16 + kq * 4 + r;
                int d = wn * 128 + nt * 16 + rr;
                size_t idx = (size_t)gm * D_BLADE + d;
                out[idx] = x[idx] + acc[mt][nt][r];
            }
}

extern "C" void kernel_launch(void* const* d_in, const int* in_sizes, int n_in,
                              void* d_out, int out_size, void* d_ws, size_t ws_size,
                              hipStream_t stream) {
    const float* x   = (const float*)d_in[0];
    const float* iw  = (const float*)d_in[1];
    const float* sg  = (const float*)d_in[2];
    const float* gg  = (const float*)d_in[3];
    const float* gwf = (const float*)d_in[4];
    const float* uwf = (const float*)d_in[5];
    const float* dwf = (const float*)d_in[6];
    const float* lnw = (const float*)d_in[7];
    const float* lnb = (const float*)d_in[8];
    float* out = (float*)d_out;

    char* ws = (char*)d_ws;
    __hip_bfloat16* nrm = (__hip_bfloat16*)ws;                       // 33.5 MB
    size_t off = (size_t)M_TOTAL * D_BLADE * 2;
    __hip_bfloat16* wgu = (__hip_bfloat16*)(ws + off);               // 1 MB
    off += (size_t)2 * D_FFN * D_BLADE * 2;
    __hip_bfloat16* dwb = (__hip_bfloat16*)(ws + off);               // 0.5 MB
    off += (size_t)D_FFN * D_BLADE * 2;
    __hip_bfloat16* h = (__hip_bfloat16*)(ws + off);

    int S = 1;
    while (S < 64 && off + ((size_t)M_TOTAL / S) * D_FFN * 2 > ws_size) S <<= 1;
    const int MS = M_TOTAL / S;

    wconv_kernel<<<dim3((D_FFN * D_BLADE) / 256), dim3(256), 0, stream>>>(gwf, uwf, dwf, wgu, dwb);
    geo_ln_kernel<<<dim3(N_TOK), dim3(256), 0, stream>>>(x, iw, sg, gg, lnw, lnb, nrm);
    for (int s = 0; s < S; ++s) {
        gu_kernel<<<dim3((MS / 128) * 16), dim3(256), 0, stream>>>(nrm, wgu, h, s * MS);
        down_kernel<<<dim3(MS / 128), dim3(256), 0, stream>>>(h, dwb, x, out, s * MS);
    }
}